// Round 8
// baseline (62725.018 us; speedup 1.0000x reference)
//
#include <hip/hip_runtime.h>

#define TSEQ 8192
#define DH   2048
#define DCAT 4096
#define ROWS 8      // hidden rows per seq workgroup (2048 / 256 WGs)
#define R3   32     // time rows per MFMA workgroup

// d_ws layout (main path): [flags u32[2][256] : 2KB][ring u32[2][512] : 4KB]
// [pad to 8KB][zx f32[TSEQ][DH] : 64MB]
#define WS_FLAGS_U32 512
#define WS_RING_U32  1024
#define WS_ZX_BYTE_OFF 8192

typedef __attribute__((ext_vector_type(8))) short bf16x8;
typedef __attribute__((ext_vector_type(4))) float f32x4;

__device__ inline short f2bf(float f) {  // RNE float->bf16
  unsigned int u = __float_as_uint(f);
  unsigned int r = (u + 0x7fffu + ((u >> 16) & 1u)) >> 16;
  return (short)r;
}

// ---------------------------------------------------------------------------
// Kernel 0: zero flags+ring (6KB). Flags hold step tags 1..8191; zero never
// matches, so stale state from a previous graph replay can't false-trigger.
// ---------------------------------------------------------------------------
__global__ void ring_init_kernel(unsigned int* __restrict__ ws32) {
  const int tid = threadIdx.x;  // 256 threads
#pragma unroll
  for (int q = 0; q < 6; ++q) ws32[q * 256 + tid] = 0u;
}

// ---------------------------------------------------------------------------
// Kernel 1 (fallback path only): sentinel-init rows 1..8191 of d_out.
// ---------------------------------------------------------------------------
__global__ void init_sentinel_kernel(float* __restrict__ out) {
  const long long n4 = ((long long)(TSEQ - 1) * DH) / 4;  // rows 1..8191
  float4* p = (float4*)(out + DH);
  float4 s;
  s.x = s.y = s.z = s.w = -1.0f;
  const long long stride = (long long)gridDim.x * blockDim.x;
  for (long long i = (long long)blockIdx.x * blockDim.x + threadIdx.x; i < n4;
       i += stride)
    p[i] = s;
}

// ---------------------------------------------------------------------------
// Kernel 2a: zx precompute (batch GEMM, MFMA): zx[t] = W_hx·caption[t-1]+b_h
// for t=1..8191, stored in d_ws. Verified template (rounds 4-7).
// ---------------------------------------------------------------------------
__global__ __launch_bounds__(256, 1) void zx_mfma_kernel(
    float* __restrict__ zx, const float* __restrict__ caption,
    const float* __restrict__ W_h, const float* __restrict__ b_h) {
  __shared__ __align__(16) short hs[R3 * 2048];  // exactly 128 KiB
  const int tid  = threadIdx.x;
  const int lane = tid & 63;
  const int wv   = tid >> 6;
  const long long ct0 = (long long)blockIdx.x * R3;  // caption row base
  const int r16  = lane & 15;
  const int kgrp = (lane >> 4) * 8;

  for (int idx = tid; idx < R3 * 256; idx += 256) {
    const int row = idx >> 8;
    const int c8  = idx & 255;
    const float* src = caption + (ct0 + row) * DH + c8 * 8;
    float4 va = *(const float4*)src;
    float4 vb = *(const float4*)(src + 4);
    bf16x8 h8;
    h8[0] = f2bf(va.x); h8[1] = f2bf(va.y); h8[2] = f2bf(va.z); h8[3] = f2bf(va.w);
    h8[4] = f2bf(vb.x); h8[5] = f2bf(vb.y); h8[6] = f2bf(vb.z); h8[7] = f2bf(vb.w);
    *(bf16x8*)&hs[row * 2048 + ((c8 * 8) ^ ((row & 7) << 3))] = h8;
  }
  __syncthreads();

  const int sw0 = (r16 & 7) << 3;

  for (int half = 0; half < 4; ++half) {
    const int n0 = wv * 512 + half * 128;
    f32x4 acc0[8], acc1[8];
#pragma unroll
    for (int j = 0; j < 8; ++j) {
      acc0[j] = (f32x4){0.f, 0.f, 0.f, 0.f};
      acc1[j] = (f32x4){0.f, 0.f, 0.f, 0.f};
    }
    for (int k0 = 0; k0 < DH; k0 += 32) {
      const int kofs = (k0 + kgrp) ^ sw0;
      bf16x8 a0 = *(const bf16x8*)&hs[r16 * 2048 + kofs];
      bf16x8 a1 = *(const bf16x8*)&hs[(16 + r16) * 2048 + kofs];
#pragma unroll
      for (int j = 0; j < 8; ++j) {
        const float* wp =
            W_h + (long long)(n0 + j * 16 + r16) * DCAT + k0 + kgrp;  // x half
        float4 wa = *(const float4*)wp;
        float4 wb = *(const float4*)(wp + 4);
        bf16x8 bfr;
        bfr[0] = f2bf(wa.x); bfr[1] = f2bf(wa.y);
        bfr[2] = f2bf(wa.z); bfr[3] = f2bf(wa.w);
        bfr[4] = f2bf(wb.x); bfr[5] = f2bf(wb.y);
        bfr[6] = f2bf(wb.z); bfr[7] = f2bf(wb.w);
        acc0[j] = __builtin_amdgcn_mfma_f32_16x16x32_bf16(a0, bfr, acc0[j], 0, 0, 0);
        acc1[j] = __builtin_amdgcn_mfma_f32_16x16x32_bf16(a1, bfr, acc1[j], 0, 0, 0);
      }
    }
#pragma unroll
    for (int j = 0; j < 8; ++j) {
      const int n = n0 + j * 16 + r16;
      const float bh = b_h[n];
#pragma unroll
      for (int r = 0; r < 4; ++r) {
        const long long z0 = ct0 + (lane >> 4) * 4 + r + 1;   // z row = cap row + 1
        if (z0 < TSEQ) zx[z0 * DH + n] = acc0[j][r] + bh;
        const long long z1 = ct0 + 16 + (lane >> 4) * 4 + r + 1;
        if (z1 < TSEQ) zx[z1 * DH + n] = acc1[j][r] + bh;
      }
    }
  }
}

// ---------------------------------------------------------------------------
// Kernel 2b: persistent sequential RNN with flag + one-shot exchange.
// 256 WGs x 512 thr; WG g owns rows [8g,8g+8); thread owns cols 4tid..4tid+3.
//
// Exchange (the r4-r7 lesson: 512 pollers/WG spamming agent loads = TB/s of
// LLC poll pressure; every round that concentrated polling got slower):
//   - producers pack h[t] rows as bf16 pairs into ring[t&1] (4KB/slot) via
//     relaxed agent u32 stores, then ONE RELEASE flag store flag[t&1][g]=t
//     (wave-granular vmcnt(0) drains the data stores first).
//   - consumers: ONLY wave 0 polls the 256 flags (1KB) with s_sleep backoff;
//     waves 1-7 park at __syncthreads issuing nothing. After detect+barrier,
//     each thread does ONE 8B agent load of its 4 cols. Agent-scope atomics
//     go to LLC -> no stale L1/L2; __syncthreads orders poll before loads.
//   - slot reuse safe: producer writes slot t&1 at step t only after seeing
//     all flags==t-1, which follows every WG's data-read of that slot for
//     t-2 (each WG's flag(t-1) release is after its reads, via red barrier).
//   - flags zeroed each launch (ring_init) so graph replays can't alias tags.
// Weights in LDS [row][2048], lane i reads base+16B*i: conflict-free (r6).
// ---------------------------------------------------------------------------
__global__ __launch_bounds__(512, 1) void seq_kernel(
    const float* __restrict__ features, const float* __restrict__ zx,
    unsigned int* __restrict__ flags, unsigned int* __restrict__ ring32,
    const float* __restrict__ W_h, float* __restrict__ out) {
  const int tid  = threadIdx.x;
  const int lane = tid & 63;
  const int wid  = tid >> 6;    // 0..7
  const int g    = blockIdx.x;
  const int rbase = g * ROWS;

  __shared__ float wlds[ROWS * 2048];   // 64 KiB, row stride 2048 floats
  __shared__ float red[2][8][8];

  // --- stage weights: wlds[r][c] = W_h[rbase+r][DH + c] ---
#pragma unroll
  for (int r = 0; r < ROWS; ++r) {
    const float* wrow = W_h + (long long)(rbase + r) * DCAT + DH;
    *(float4*)&wlds[r * 2048 + 4 * tid] = *(const float4*)(wrow + 4 * tid);
  }
  __syncthreads();

  for (int t = 1; t < TSEQ; ++t) {
    // issue weight ds_reads first (latency hides under the wait)
    float4 wr[ROWS];
#pragma unroll
    for (int r = 0; r < ROWS; ++r)
      wr[r] = *(const float4*)&wlds[r * 2048 + 4 * tid];

    // finisher lanes prefetch this step's zx values (no dependency)
    float zpre = 0.0f;
    if (tid < ROWS) zpre = zx[(long long)t * DH + rbase + tid];

    float a[4];
    if (t == 1) {
      float4 f4 = *(const float4*)(features + 4 * tid);
      a[0] = f4.x; a[1] = f4.y; a[2] = f4.z; a[3] = f4.w;
    } else {
      const int slot = (t - 1) & 1;
      if (wid == 0) {
        // wave 0 polls all 256 flags as 128 u64 (lane, lane+64)
        const unsigned long long* f64 =
            (const unsigned long long*)(flags + slot * 256);
        const unsigned long long e =
            ((unsigned long long)(unsigned int)(t - 1) << 32) |
            (unsigned int)(t - 1);
        for (;;) {
          unsigned long long v0 = __hip_atomic_load(
              f64 + lane, __ATOMIC_RELAXED, __HIP_MEMORY_SCOPE_AGENT);
          unsigned long long v1 = __hip_atomic_load(
              f64 + 64 + lane, __ATOMIC_RELAXED, __HIP_MEMORY_SCOPE_AGENT);
          if (__all(v0 == e && v1 == e)) break;
          __builtin_amdgcn_s_sleep(2);
        }
      }
      __syncthreads();
      // one-shot: own 4 cols (one u64) from the LLC-resident ring
      const unsigned long long* d64 =
          (const unsigned long long*)(ring32 + slot * 512);
      unsigned long long u = __hip_atomic_load(d64 + tid, __ATOMIC_RELAXED,
                                               __HIP_MEMORY_SCOPE_AGENT);
      const unsigned int lo = (unsigned int)u;
      const unsigned int hi = (unsigned int)(u >> 32);
      a[0] = __uint_as_float(lo << 16);
      a[1] = __uint_as_float(lo & 0xFFFF0000u);
      a[2] = __uint_as_float(hi << 16);
      a[3] = __uint_as_float(hi & 0xFFFF0000u);
    }

    // --- per-thread partials: 8 rows x 4 consecutive cols ---
    float vv[8];
#pragma unroll
    for (int r = 0; r < ROWS; ++r)
      vv[r] = wr[r].x * a[0] + wr[r].y * a[1] + wr[r].z * a[2] + wr[r].w * a[3];

    // --- folded wave reduction (verified rounds 1-7): lanes 0..7 get rows ---
    {
      const bool up = lane & 1;
#pragma unroll
      for (int j = 0; j < 4; ++j) {
        float send  = up ? vv[j] : vv[j + 4];
        float other = __shfl_xor(send, 1, 64);
        vv[j] = (up ? vv[j + 4] : vv[j]) + other;
      }
    }
    {
      const bool up = lane & 2;
#pragma unroll
      for (int j = 0; j < 2; ++j) {
        float send  = up ? vv[j] : vv[j + 2];
        float other = __shfl_xor(send, 2, 64);
        vv[j] = (up ? vv[j + 2] : vv[j]) + other;
      }
    }
    {
      const bool up = lane & 4;
      float send  = up ? vv[0] : vv[1];
      float other = __shfl_xor(send, 4, 64);
      vv[0] = (up ? vv[1] : vv[0]) + other;
    }
    float v = vv[0];
    v += __shfl_xor(v, 8, 64);
    v += __shfl_xor(v, 16, 64);
    v += __shfl_xor(v, 32, 64);
    if (lane < 8) {
      const int row = ((lane & 1) << 2) | (lane & 2) | ((lane >> 2) & 1);
      red[t & 1][wid][row] = v;
    }
    __syncthreads();

    // --- wave-0 tail: sum over wids, sigmoid, publish data then flag ---
    if (tid < 64) {
      float s = red[t & 1][tid >> 3][tid & 7];
      s += __shfl_xor(s, 8, 64);
      s += __shfl_xor(s, 16, 64);
      s += __shfl_xor(s, 32, 64);
      if (tid < ROWS) {
        float h = 1.0f / (1.0f + __expf(-(s + zpre)));
        out[(long long)t * DH + rbase + tid] = h;  // f32, off critical path
        float hb = __shfl_down(h, 1, 64);          // partner (odd) column
        if ((tid & 1) == 0) {
          unsigned int pkt = ((unsigned int)(unsigned short)f2bf(h)) |
                             ((unsigned int)(unsigned short)f2bf(hb) << 16);
          __hip_atomic_store(ring32 + (t & 1) * 512 + (rbase >> 1) + (tid >> 1),
                             pkt, __ATOMIC_RELAXED, __HIP_MEMORY_SCOPE_AGENT);
        }
        if (tid == 0)
          __hip_atomic_store(flags + (t & 1) * 256 + g, (unsigned int)t,
                             __ATOMIC_RELEASE, __HIP_MEMORY_SCOPE_AGENT);
      }
    }
  }
}

// ---------------------------------------------------------------------------
// Kernel 2-fallback (ws too small): round-4/6 verified sentinel-spin kernel.
// ---------------------------------------------------------------------------
__global__ __launch_bounds__(512, 1) void seq_kernel_fb(
    const float* __restrict__ features, const float* __restrict__ caption,
    const float* __restrict__ W_h, const float* __restrict__ b_h,
    float* __restrict__ out) {
  const int tid  = threadIdx.x;
  const int i    = tid & 255;
  const int part = tid >> 8;
  const int rbase = blockIdx.x * ROWS;
  const int lane = tid & 63;
  const int wid  = tid >> 6;

  __shared__ float wlds[512 * 64];
  __shared__ float red[8][ROWS];

  const int swz = (tid & 7) << 2;
#pragma unroll
  for (int r = 0; r < ROWS; ++r) {
    const float* wrow = W_h + (long long)(rbase + r) * DCAT + part * DH;
#pragma unroll
    for (int q = 0; q < 4; ++q) {
      float2 wv = *(const float2*)(wrow + q * 512 + i * 2);
      const int lofs = r * 8 + q * 2;
      *(float2*)&wlds[tid * 64 + (((lofs & ~3) ^ swz) | (lofs & 3))] = wv;
    }
  }
  const float bias = (tid < ROWS) ? b_h[rbase + tid] : 0.0f;
  __syncthreads();

  float an[8];
  if (part == 0) {
#pragma unroll
    for (int q = 0; q < 4; ++q) {
      float2 xv = *(const float2*)(caption + q * 512 + i * 2);
      an[2 * q]     = xv.x;
      an[2 * q + 1] = xv.y;
    }
  }

  for (int t = 1; t < TSEQ; ++t) {
    float4 wr0[ROWS], wr1[ROWS];
#pragma unroll
    for (int r = 0; r < ROWS; ++r) {
      wr0[r] = *(const float4*)&wlds[tid * 64 + ((r * 8) ^ swz)];
      wr1[r] = *(const float4*)&wlds[tid * 64 + ((r * 8 + 4) ^ swz)];
    }

    float a[8];
    if (part == 0) {
#pragma unroll
      for (int j = 0; j < 8; ++j) a[j] = an[j];
      const float* xn = caption + (long long)t * DH;
#pragma unroll
      for (int q = 0; q < 4; ++q) {
        float2 xv = *(const float2*)(xn + q * 512 + i * 2);
        an[2 * q]     = xv.x;
        an[2 * q + 1] = xv.y;
      }
    } else if (t == 1) {
#pragma unroll
      for (int q = 0; q < 4; ++q) {
        float2 xv = *(const float2*)(features + q * 512 + i * 2);
        a[2 * q]     = xv.x;
        a[2 * q + 1] = xv.y;
      }
    } else {
      const unsigned long long* hrow =
          (const unsigned long long*)(out + (long long)(t - 1) * DH);
      unsigned long long v[4];
      for (;;) {
        unsigned long long m = 0ull;
#pragma unroll
        for (int q = 0; q < 4; ++q) {
          v[q] = __hip_atomic_load(hrow + q * 256 + i, __ATOMIC_RELAXED,
                                   __HIP_MEMORY_SCOPE_AGENT);
          m |= v[q];
        }
        if ((m & 0x8000000080000000ull) == 0ull) break;
        __builtin_amdgcn_s_sleep(1);
      }
#pragma unroll
      for (int q = 0; q < 4; ++q) {
        a[2 * q]     = __uint_as_float((unsigned int)v[q]);
        a[2 * q + 1] = __uint_as_float((unsigned int)(v[q] >> 32));
      }
    }

    float acc[ROWS];
#pragma unroll
    for (int r = 0; r < ROWS; ++r) {
      acc[r] = wr0[r].x * a[0] + wr0[r].y * a[1] + wr0[r].z * a[2] +
               wr0[r].w * a[3] + wr1[r].x * a[4] + wr1[r].y * a[5] +
               wr1[r].z * a[6] + wr1[r].w * a[7];
    }

    float vv[8];
#pragma unroll
    for (int r = 0; r < ROWS; ++r) vv[r] = acc[r];
    {
      const bool up = lane & 1;
#pragma unroll
      for (int j = 0; j < 4; ++j) {
        float send  = up ? vv[j] : vv[j + 4];
        float other = __shfl_xor(send, 1, 64);
        vv[j] = (up ? vv[j + 4] : vv[j]) + other;
      }
    }
    {
      const bool up = lane & 2;
#pragma unroll
      for (int j = 0; j < 2; ++j) {
        float send  = up ? vv[j] : vv[j + 2];
        float other = __shfl_xor(send, 2, 64);
        vv[j] = (up ? vv[j + 2] : vv[j]) + other;
      }
    }
    {
      const bool up = lane & 4;
      float send  = up ? vv[0] : vv[1];
      float other = __shfl_xor(send, 4, 64);
      vv[0] = (up ? vv[1] : vv[0]) + other;
    }
    float v = vv[0];
    v += __shfl_xor(v, 8, 64);
    v += __shfl_xor(v, 16, 64);
    v += __shfl_xor(v, 32, 64);
    if (lane < 8) {
      const int row = ((lane & 1) << 2) | (lane & 2) | ((lane >> 2) & 1);
      red[wid][row] = v;
    }
    __syncthreads();

    if (tid < ROWS) {
      float z = bias;
#pragma unroll
      for (int wv2 = 0; wv2 < 8; ++wv2) z += red[wv2][tid];
      float h = 1.0f / (1.0f + __expf(-z));
      __hip_atomic_store((unsigned int*)(out + (long long)t * DH + rbase + tid),
                         __float_as_uint(h), __ATOMIC_RELAXED,
                         __HIP_MEMORY_SCOPE_AGENT);
    }
    __syncthreads();
  }
}

// ---------------------------------------------------------------------------
// Kernel 3: output projection via bf16 MFMA, IN PLACE on d_out (verified).
// ---------------------------------------------------------------------------
__global__ __launch_bounds__(256, 1) void out_mfma_kernel(
    float* __restrict__ out, const float* __restrict__ W_o,
    const float* __restrict__ b_o, const float* __restrict__ caption) {
  __shared__ __align__(16) short hs[R3 * 2048];  // exactly 128 KiB
  const int tid  = threadIdx.x;
  const int lane = tid & 63;
  const int wv   = tid >> 6;
  const long long t0 = (long long)blockIdx.x * R3;
  const int r16  = lane & 15;
  const int kgrp = (lane >> 4) * 8;

  for (int idx = tid; idx < R3 * 256; idx += 256) {
    const int row = idx >> 8;
    const int c8  = idx & 255;
    const float* src = out + (t0 + row) * DH + c8 * 8;
    float4 va = *(const float4*)src;
    float4 vb = *(const float4*)(src + 4);
    bf16x8 h8;
    h8[0] = f2bf(va.x); h8[1] = f2bf(va.y); h8[2] = f2bf(va.z); h8[3] = f2bf(va.w);
    h8[4] = f2bf(vb.x); h8[5] = f2bf(vb.y); h8[6] = f2bf(vb.z); h8[7] = f2bf(vb.w);
    *(bf16x8*)&hs[row * 2048 + ((c8 * 8) ^ ((row & 7) << 3))] = h8;
  }
  __syncthreads();

  const int sw0 = (r16 & 7) << 3;

  for (int half = 0; half < 4; ++half) {
    const int n0 = wv * 512 + half * 128;
    f32x4 acc0[8], acc1[8];
#pragma unroll
    for (int j = 0; j < 8; ++j) {
      acc0[j] = (f32x4){0.f, 0.f, 0.f, 0.f};
      acc1[j] = (f32x4){0.f, 0.f, 0.f, 0.f};
    }
    for (int k0 = 0; k0 < DH; k0 += 32) {
      const int kofs = (k0 + kgrp) ^ sw0;
      bf16x8 a0 = *(const bf16x8*)&hs[r16 * 2048 + kofs];
      bf16x8 a1 = *(const bf16x8*)&hs[(16 + r16) * 2048 + kofs];
#pragma unroll
      for (int j = 0; j < 8; ++j) {
        const float* wp =
            W_o + (long long)(n0 + j * 16 + r16) * DH + k0 + kgrp;
        float4 wa = *(const float4*)wp;
        float4 wb = *(const float4*)(wp + 4);
        bf16x8 bfr;
        bfr[0] = f2bf(wa.x); bfr[1] = f2bf(wa.y);
        bfr[2] = f2bf(wa.z); bfr[3] = f2bf(wa.w);
        bfr[4] = f2bf(wb.x); bfr[5] = f2bf(wb.y);
        bfr[6] = f2bf(wb.z); bfr[7] = f2bf(wb.w);
        acc0[j] = __builtin_amdgcn_mfma_f32_16x16x32_bf16(a0, bfr, acc0[j], 0, 0, 0);
        acc1[j] = __builtin_amdgcn_mfma_f32_16x16x32_bf16(a1, bfr, acc1[j], 0, 0, 0);
      }
    }
#pragma unroll
    for (int j = 0; j < 8; ++j) {
      const int n = n0 + j * 16 + r16;
      const float bo = b_o[n];
#pragma unroll
      for (int r = 0; r < 4; ++r) {
        const long long row0 = t0 + (lane >> 4) * 4 + r;
        float v0 = 1.0f / (1.0f + __expf(-(acc0[j][r] + bo)));
        if (row0 == 0) v0 = caption[n];  // output[0] = caption[0]
        out[row0 * DH + n] = v0;
        const long long row1 = t0 + 16 + (lane >> 4) * 4 + r;
        float v1 = 1.0f / (1.0f + __expf(-(acc1[j][r] + bo)));
        out[row1 * DH + n] = v1;
      }
    }
  }
}

// ---------------------------------------------------------------------------
extern "C" void kernel_launch(void* const* d_in, const int* in_sizes, int n_in,
                              void* d_out, int out_size, void* d_ws,
                              size_t ws_size, hipStream_t stream) {
  const float* features = (const float*)d_in[0];
  const float* caption  = (const float*)d_in[1];
  const float* W_h      = (const float*)d_in[2];
  const float* b_h      = (const float*)d_in[3];
  const float* W_o      = (const float*)d_in[4];
  const float* b_o      = (const float*)d_in[5];
  float* out = (float*)d_out;

  const size_t zx_bytes = (size_t)TSEQ * DH * sizeof(float);

  if (ws_size >= WS_ZX_BYTE_OFF + zx_bytes) {
    unsigned int* ws32 = (unsigned int*)d_ws;
    unsigned int* flags = ws32;                    // u32[2][256]
    unsigned int* ring32 = ws32 + WS_FLAGS_U32;    // u32[2][512]
    float* zx = (float*)((char*)d_ws + WS_ZX_BYTE_OFF);
    hipLaunchKernelGGL(ring_init_kernel, dim3(1), dim3(256), 0, stream, ws32);
    hipLaunchKernelGGL(zx_mfma_kernel, dim3(TSEQ / R3), dim3(256), 0, stream,
                       zx, caption, W_h, b_h);
    hipLaunchKernelGGL(seq_kernel, dim3(DH / ROWS), dim3(512), 0, stream,
                       features, zx, flags, ring32, W_h, out);
  } else {
    hipLaunchKernelGGL(init_sentinel_kernel, dim3(2048), dim3(256), 0, stream,
                       out);
    hipLaunchKernelGGL(seq_kernel_fb, dim3(DH / ROWS), dim3(512), 0, stream,
                       features, caption, W_h, b_h, out);
  }

  hipLaunchKernelGGL(out_mfma_kernel, dim3(TSEQ / R3), dim3(256), 0, stream,
                     out, W_o, b_o, caption);
}

// Round 9
// 16400.558 us; speedup vs baseline: 3.8246x; 3.8246x over previous
//
#include <hip/hip_runtime.h>

#define TSEQ 8192
#define DH   2048
#define DCAT 4096
#define ROWS 8      // hidden rows per seq workgroup (2048 / 256 WGs)
#define R3   32     // time rows per MFMA workgroup

typedef __attribute__((ext_vector_type(8))) short bf16x8;
typedef __attribute__((ext_vector_type(4))) float f32x4;

__device__ inline short f2bf(float f) {  // RNE float->bf16
  unsigned int u = __float_as_uint(f);
  unsigned int r = (u + 0x7fffu + ((u >> 16) & 1u)) >> 16;
  return (short)r;
}

// ---------------------------------------------------------------------------
// Kernel 1: sentinel-init rows 1..8191 of d_out (h exchange buffer).
// Valid h values are sigmoid outputs (sign bit 0); sentinel -1.0f has sign 1.
// Runs every launch (harness does not re-poison between replays).
// ---------------------------------------------------------------------------
__global__ void init_sentinel_kernel(float* __restrict__ out) {
  const long long n4 = ((long long)(TSEQ - 1) * DH) / 4;  // rows 1..8191
  float4* p = (float4*)(out + DH);
  float4 s;
  s.x = s.y = s.z = s.w = -1.0f;
  const long long stride = (long long)gridDim.x * blockDim.x;
  for (long long i = (long long)blockIdx.x * blockDim.x + threadIdx.x; i < n4;
       i += stride)
    p[i] = s;
}

// ---------------------------------------------------------------------------
// Kernel 2a: zx precompute (batch GEMM, MFMA): zx[t] = W_hx·caption[t-1]+b_h
// for t=1..8191, stored in d_ws. Verified template (rounds 4-8).
// ---------------------------------------------------------------------------
__global__ __launch_bounds__(256, 1) void zx_mfma_kernel(
    float* __restrict__ zx, const float* __restrict__ caption,
    const float* __restrict__ W_h, const float* __restrict__ b_h) {
  __shared__ __align__(16) short hs[R3 * 2048];  // exactly 128 KiB
  const int tid  = threadIdx.x;
  const int lane = tid & 63;
  const int wv   = tid >> 6;
  const long long ct0 = (long long)blockIdx.x * R3;  // caption row base
  const int r16  = lane & 15;
  const int kgrp = (lane >> 4) * 8;

  for (int idx = tid; idx < R3 * 256; idx += 256) {
    const int row = idx >> 8;
    const int c8  = idx & 255;
    const float* src = caption + (ct0 + row) * DH + c8 * 8;
    float4 va = *(const float4*)src;
    float4 vb = *(const float4*)(src + 4);
    bf16x8 h8;
    h8[0] = f2bf(va.x); h8[1] = f2bf(va.y); h8[2] = f2bf(va.z); h8[3] = f2bf(va.w);
    h8[4] = f2bf(vb.x); h8[5] = f2bf(vb.y); h8[6] = f2bf(vb.z); h8[7] = f2bf(vb.w);
    *(bf16x8*)&hs[row * 2048 + ((c8 * 8) ^ ((row & 7) << 3))] = h8;
  }
  __syncthreads();

  const int sw0 = (r16 & 7) << 3;

  for (int half = 0; half < 4; ++half) {
    const int n0 = wv * 512 + half * 128;
    f32x4 acc0[8], acc1[8];
#pragma unroll
    for (int j = 0; j < 8; ++j) {
      acc0[j] = (f32x4){0.f, 0.f, 0.f, 0.f};
      acc1[j] = (f32x4){0.f, 0.f, 0.f, 0.f};
    }
    for (int k0 = 0; k0 < DH; k0 += 32) {
      const int kofs = (k0 + kgrp) ^ sw0;
      bf16x8 a0 = *(const bf16x8*)&hs[r16 * 2048 + kofs];
      bf16x8 a1 = *(const bf16x8*)&hs[(16 + r16) * 2048 + kofs];
#pragma unroll
      for (int j = 0; j < 8; ++j) {
        const float* wp =
            W_h + (long long)(n0 + j * 16 + r16) * DCAT + k0 + kgrp;  // x half
        float4 wa = *(const float4*)wp;
        float4 wb = *(const float4*)(wp + 4);
        bf16x8 bfr;
        bfr[0] = f2bf(wa.x); bfr[1] = f2bf(wa.y);
        bfr[2] = f2bf(wa.z); bfr[3] = f2bf(wa.w);
        bfr[4] = f2bf(wb.x); bfr[5] = f2bf(wb.y);
        bfr[6] = f2bf(wb.z); bfr[7] = f2bf(wb.w);
        acc0[j] = __builtin_amdgcn_mfma_f32_16x16x32_bf16(a0, bfr, acc0[j], 0, 0, 0);
        acc1[j] = __builtin_amdgcn_mfma_f32_16x16x32_bf16(a1, bfr, acc1[j], 0, 0, 0);
      }
    }
#pragma unroll
    for (int j = 0; j < 8; ++j) {
      const int n = n0 + j * 16 + r16;
      const float bh = b_h[n];
#pragma unroll
      for (int r = 0; r < 4; ++r) {
        const long long z0 = ct0 + (lane >> 4) * 4 + r + 1;   // z row = cap row + 1
        if (z0 < TSEQ) zx[z0 * DH + n] = acc0[j][r] + bh;
        const long long z1 = ct0 + 16 + (lane >> 4) * 4 + r + 1;
        if (z1 < TSEQ) zx[z1 * DH + n] = acc1[j][r] + bh;
      }
    }
  }
}

// ---------------------------------------------------------------------------
// Kernel 2b: persistent sequential RNN (r6-verified structure + two fixes).
// 256 WGs x 512 thr; WG g owns rows [8g,8g+8); thread owns cols 4tid..4tid+3.
//   Fix 1 (r8 post-mortem): zx is consumed via a depth-2 register FIFO —
//     at step t the finisher uses z0 (loaded at t-2) and issues the load for
//     t+2. The ~900-cyc cold-HBM zx miss is no longer on the producer tail
//     (this was the hidden regression source in r6/r7/r8).
//   Fix 2: weights are read from LDS into registers ONCE, pinned with asm
//     keep-alives; the per-step 8x ds_read_b128 + lgkm waits are gone.
// Exchange identical to r6 (passed, 2.07us/step): sentinel spin on d_out
// rows with s_sleep(1), relaxed agent atomics only (NO release — r8 showed
// agent-release triggers per-step L2 flush), one barrier per step, red
// double-buffered by t&1 (race-ahead safety argument in r6 comments held).
// ---------------------------------------------------------------------------
__global__ __launch_bounds__(512, 1) void seq_kernel(
    const float* __restrict__ features, const float* __restrict__ zx,
    const float* __restrict__ W_h, float* __restrict__ out) {
  const int tid  = threadIdx.x;
  const int lane = tid & 63;
  const int wid  = tid >> 6;    // 0..7
  const int rbase = blockIdx.x * ROWS;

  __shared__ float wlds[ROWS * 2048];   // 64 KiB, row stride 2048 floats
  __shared__ float red[2][8][8];

  // --- stage weights global -> LDS (firewall against sink-to-global) ---
#pragma unroll
  for (int r = 0; r < ROWS; ++r) {
    const float* wrow = W_h + (long long)(rbase + r) * DCAT + DH;
    *(float4*)&wlds[r * 2048 + 4 * tid] = *(const float4*)(wrow + 4 * tid);
  }
  __syncthreads();

  // --- LDS -> registers once; pin so the compiler can't sink the reads ---
  float4 wr[ROWS];
#pragma unroll
  for (int r = 0; r < ROWS; ++r)
    wr[r] = *(const float4*)&wlds[r * 2048 + 4 * tid];
  asm volatile("" : "+v"(wr[0].x), "+v"(wr[0].y), "+v"(wr[0].z), "+v"(wr[0].w),
                    "+v"(wr[1].x), "+v"(wr[1].y), "+v"(wr[1].z), "+v"(wr[1].w),
                    "+v"(wr[2].x), "+v"(wr[2].y), "+v"(wr[2].z), "+v"(wr[2].w),
                    "+v"(wr[3].x), "+v"(wr[3].y), "+v"(wr[3].z), "+v"(wr[3].w));
  asm volatile("" : "+v"(wr[4].x), "+v"(wr[4].y), "+v"(wr[4].z), "+v"(wr[4].w),
                    "+v"(wr[5].x), "+v"(wr[5].y), "+v"(wr[5].z), "+v"(wr[5].w),
                    "+v"(wr[6].x), "+v"(wr[6].y), "+v"(wr[6].z), "+v"(wr[6].w),
                    "+v"(wr[7].x), "+v"(wr[7].y), "+v"(wr[7].z), "+v"(wr[7].w));

  // --- prime the depth-2 zx FIFO (finisher lanes only) ---
  float z0 = 0.0f, z1 = 0.0f;
  if (tid < ROWS) {
    z0 = zx[(long long)1 * DH + rbase + tid];
    z1 = zx[(long long)2 * DH + rbase + tid];
  }

  for (int t = 1; t < TSEQ; ++t) {
    // issue zx prefetch for step t+2 (2 steps of latency cover)
    float zn = 0.0f;
    if (tid < ROWS) {
      const int tp = (t + 2 < TSEQ) ? t + 2 : TSEQ - 1;
      zn = zx[(long long)tp * DH + rbase + tid];
    }

    float a[4];
    if (t == 1) {
      float4 f4 = *(const float4*)(features + 4 * tid);
      a[0] = f4.x; a[1] = f4.y; a[2] = f4.z; a[3] = f4.w;
    } else {
      // spin on own columns of h[t-1]: contiguous 16B, sign-bit ready flag
      const unsigned long long* hrow =
          (const unsigned long long*)(out + (long long)(t - 1) * DH);
      unsigned long long v0, v1;
      v0 = __hip_atomic_load(hrow + 2 * tid, __ATOMIC_RELAXED,
                             __HIP_MEMORY_SCOPE_AGENT);
      v1 = __hip_atomic_load(hrow + 2 * tid + 1, __ATOMIC_RELAXED,
                             __HIP_MEMORY_SCOPE_AGENT);
      while (((v0 | v1) & 0x8000000080000000ull) != 0ull) {
        __builtin_amdgcn_s_sleep(1);
        v0 = __hip_atomic_load(hrow + 2 * tid, __ATOMIC_RELAXED,
                               __HIP_MEMORY_SCOPE_AGENT);
        v1 = __hip_atomic_load(hrow + 2 * tid + 1, __ATOMIC_RELAXED,
                               __HIP_MEMORY_SCOPE_AGENT);
      }
      a[0] = __uint_as_float((unsigned int)v0);
      a[1] = __uint_as_float((unsigned int)(v0 >> 32));
      a[2] = __uint_as_float((unsigned int)v1);
      a[3] = __uint_as_float((unsigned int)(v1 >> 32));
    }

    // --- per-thread partials: 8 rows x 4 consecutive cols (regs only) ---
    float vv[8];
#pragma unroll
    for (int r = 0; r < ROWS; ++r)
      vv[r] = wr[r].x * a[0] + wr[r].y * a[1] + wr[r].z * a[2] + wr[r].w * a[3];

    // --- folded wave reduction (verified rounds 1-8): lanes 0..7 get rows ---
    {
      const bool up = lane & 1;
#pragma unroll
      for (int j = 0; j < 4; ++j) {
        float send  = up ? vv[j] : vv[j + 4];
        float other = __shfl_xor(send, 1, 64);
        vv[j] = (up ? vv[j + 4] : vv[j]) + other;
      }
    }
    {
      const bool up = lane & 2;
#pragma unroll
      for (int j = 0; j < 2; ++j) {
        float send  = up ? vv[j] : vv[j + 2];
        float other = __shfl_xor(send, 2, 64);
        vv[j] = (up ? vv[j + 2] : vv[j]) + other;
      }
    }
    {
      const bool up = lane & 4;
      float send  = up ? vv[0] : vv[1];
      float other = __shfl_xor(send, 4, 64);
      vv[0] = (up ? vv[1] : vv[0]) + other;
    }
    float v = vv[0];
    v += __shfl_xor(v, 8, 64);
    v += __shfl_xor(v, 16, 64);
    v += __shfl_xor(v, 32, 64);
    if (lane < 8) {
      const int row = ((lane & 1) << 2) | (lane & 2) | ((lane >> 2) & 1);
      red[t & 1][wid][row] = v;
    }
    __syncthreads();

    // --- wave-0 tail: sum over wids (3 shuffles), sigmoid, publish ---
    if (tid < 64) {
      float s = red[t & 1][tid >> 3][tid & 7];
      s += __shfl_xor(s, 8, 64);
      s += __shfl_xor(s, 16, 64);
      s += __shfl_xor(s, 32, 64);
      if (tid < ROWS) {
        float h = 1.0f / (1.0f + __expf(-(s + z0)));
        __hip_atomic_store(
            (unsigned int*)(out + (long long)t * DH + rbase + tid),
            __float_as_uint(h), __ATOMIC_RELAXED, __HIP_MEMORY_SCOPE_AGENT);
      }
    }
    // shift the zx FIFO
    z0 = z1;
    z1 = zn;
  }
}

// ---------------------------------------------------------------------------
// Kernel 2-fallback (ws too small): round-4/6 verified sentinel-spin kernel.
// ---------------------------------------------------------------------------
__global__ __launch_bounds__(512, 1) void seq_kernel_fb(
    const float* __restrict__ features, const float* __restrict__ caption,
    const float* __restrict__ W_h, const float* __restrict__ b_h,
    float* __restrict__ out) {
  const int tid  = threadIdx.x;
  const int i    = tid & 255;
  const int part = tid >> 8;
  const int rbase = blockIdx.x * ROWS;
  const int lane = tid & 63;
  const int wid  = tid >> 6;

  __shared__ float wlds[512 * 64];
  __shared__ float red[8][ROWS];

  const int swz = (tid & 7) << 2;
#pragma unroll
  for (int r = 0; r < ROWS; ++r) {
    const float* wrow = W_h + (long long)(rbase + r) * DCAT + part * DH;
#pragma unroll
    for (int q = 0; q < 4; ++q) {
      float2 wv = *(const float2*)(wrow + q * 512 + i * 2);
      const int lofs = r * 8 + q * 2;
      *(float2*)&wlds[tid * 64 + (((lofs & ~3) ^ swz) | (lofs & 3))] = wv;
    }
  }
  const float bias = (tid < ROWS) ? b_h[rbase + tid] : 0.0f;
  __syncthreads();

  float an[8];
  if (part == 0) {
#pragma unroll
    for (int q = 0; q < 4; ++q) {
      float2 xv = *(const float2*)(caption + q * 512 + i * 2);
      an[2 * q]     = xv.x;
      an[2 * q + 1] = xv.y;
    }
  }

  for (int t = 1; t < TSEQ; ++t) {
    float4 wr0[ROWS], wr1[ROWS];
#pragma unroll
    for (int r = 0; r < ROWS; ++r) {
      wr0[r] = *(const float4*)&wlds[tid * 64 + ((r * 8) ^ swz)];
      wr1[r] = *(const float4*)&wlds[tid * 64 + ((r * 8 + 4) ^ swz)];
    }

    float a[8];
    if (part == 0) {
#pragma unroll
      for (int j = 0; j < 8; ++j) a[j] = an[j];
      const float* xn = caption + (long long)t * DH;
#pragma unroll
      for (int q = 0; q < 4; ++q) {
        float2 xv = *(const float2*)(xn + q * 512 + i * 2);
        an[2 * q]     = xv.x;
        an[2 * q + 1] = xv.y;
      }
    } else if (t == 1) {
#pragma unroll
      for (int q = 0; q < 4; ++q) {
        float2 xv = *(const float2*)(features + q * 512 + i * 2);
        a[2 * q]     = xv.x;
        a[2 * q + 1] = xv.y;
      }
    } else {
      const unsigned long long* hrow =
          (const unsigned long long*)(out + (long long)(t - 1) * DH);
      unsigned long long v[4];
      for (;;) {
        unsigned long long m = 0ull;
#pragma unroll
        for (int q = 0; q < 4; ++q) {
          v[q] = __hip_atomic_load(hrow + q * 256 + i, __ATOMIC_RELAXED,
                                   __HIP_MEMORY_SCOPE_AGENT);
          m |= v[q];
        }
        if ((m & 0x8000000080000000ull) == 0ull) break;
        __builtin_amdgcn_s_sleep(1);
      }
#pragma unroll
      for (int q = 0; q < 4; ++q) {
        a[2 * q]     = __uint_as_float((unsigned int)v[q]);
        a[2 * q + 1] = __uint_as_float((unsigned int)(v[q] >> 32));
      }
    }

    float acc[ROWS];
#pragma unroll
    for (int r = 0; r < ROWS; ++r) {
      acc[r] = wr0[r].x * a[0] + wr0[r].y * a[1] + wr0[r].z * a[2] +
               wr0[r].w * a[3] + wr1[r].x * a[4] + wr1[r].y * a[5] +
               wr1[r].z * a[6] + wr1[r].w * a[7];
    }

    float vv[8];
#pragma unroll
    for (int r = 0; r < ROWS; ++r) vv[r] = acc[r];
    {
      const bool up = lane & 1;
#pragma unroll
      for (int j = 0; j < 4; ++j) {
        float send  = up ? vv[j] : vv[j + 4];
        float other = __shfl_xor(send, 1, 64);
        vv[j] = (up ? vv[j + 4] : vv[j]) + other;
      }
    }
    {
      const bool up = lane & 2;
#pragma unroll
      for (int j = 0; j < 2; ++j) {
        float send  = up ? vv[j] : vv[j + 2];
        float other = __shfl_xor(send, 2, 64);
        vv[j] = (up ? vv[j + 2] : vv[j]) + other;
      }
    }
    {
      const bool up = lane & 4;
      float send  = up ? vv[0] : vv[1];
      float other = __shfl_xor(send, 4, 64);
      vv[0] = (up ? vv[1] : vv[0]) + other;
    }
    float v = vv[0];
    v += __shfl_xor(v, 8, 64);
    v += __shfl_xor(v, 16, 64);
    v += __shfl_xor(v, 32, 64);
    if (lane < 8) {
      const int row = ((lane & 1) << 2) | (lane & 2) | ((lane >> 2) & 1);
      red[wid][row] = v;
    }
    __syncthreads();

    if (tid < ROWS) {
      float z = bias;
#pragma unroll
      for (int wv2 = 0; wv2 < 8; ++wv2) z += red[wv2][tid];
      float h = 1.0f / (1.0f + __expf(-z));
      __hip_atomic_store((unsigned int*)(out + (long long)t * DH + rbase + tid),
                         __float_as_uint(h), __ATOMIC_RELAXED,
                         __HIP_MEMORY_SCOPE_AGENT);
    }
    __syncthreads();
  }
}

// ---------------------------------------------------------------------------
// Kernel 3: output projection via bf16 MFMA, IN PLACE on d_out (verified).
// ---------------------------------------------------------------------------
__global__ __launch_bounds__(256, 1) void out_mfma_kernel(
    float* __restrict__ out, const float* __restrict__ W_o,
    const float* __restrict__ b_o, const float* __restrict__ caption) {
  __shared__ __align__(16) short hs[R3 * 2048];  // exactly 128 KiB
  const int tid  = threadIdx.x;
  const int lane = tid & 63;
  const int wv   = tid >> 6;
  const long long t0 = (long long)blockIdx.x * R3;
  const int r16  = lane & 15;
  const int kgrp = (lane >> 4) * 8;

  for (int idx = tid; idx < R3 * 256; idx += 256) {
    const int row = idx >> 8;
    const int c8  = idx & 255;
    const float* src = out + (t0 + row) * DH + c8 * 8;
    float4 va = *(const float4*)src;
    float4 vb = *(const float4*)(src + 4);
    bf16x8 h8;
    h8[0] = f2bf(va.x); h8[1] = f2bf(va.y); h8[2] = f2bf(va.z); h8[3] = f2bf(va.w);
    h8[4] = f2bf(vb.x); h8[5] = f2bf(vb.y); h8[6] = f2bf(vb.z); h8[7] = f2bf(vb.w);
    *(bf16x8*)&hs[row * 2048 + ((c8 * 8) ^ ((row & 7) << 3))] = h8;
  }
  __syncthreads();

  const int sw0 = (r16 & 7) << 3;

  for (int half = 0; half < 4; ++half) {
    const int n0 = wv * 512 + half * 128;
    f32x4 acc0[8], acc1[8];
#pragma unroll
    for (int j = 0; j < 8; ++j) {
      acc0[j] = (f32x4){0.f, 0.f, 0.f, 0.f};
      acc1[j] = (f32x4){0.f, 0.f, 0.f, 0.f};
    }
    for (int k0 = 0; k0 < DH; k0 += 32) {
      const int kofs = (k0 + kgrp) ^ sw0;
      bf16x8 a0 = *(const bf16x8*)&hs[r16 * 2048 + kofs];
      bf16x8 a1 = *(const bf16x8*)&hs[(16 + r16) * 2048 + kofs];
#pragma unroll
      for (int j = 0; j < 8; ++j) {
        const float* wp =
            W_o + (long long)(n0 + j * 16 + r16) * DH + k0 + kgrp;
        float4 wa = *(const float4*)wp;
        float4 wb = *(const float4*)(wp + 4);
        bf16x8 bfr;
        bfr[0] = f2bf(wa.x); bfr[1] = f2bf(wa.y);
        bfr[2] = f2bf(wa.z); bfr[3] = f2bf(wa.w);
        bfr[4] = f2bf(wb.x); bfr[5] = f2bf(wb.y);
        bfr[6] = f2bf(wb.z); bfr[7] = f2bf(wb.w);
        acc0[j] = __builtin_amdgcn_mfma_f32_16x16x32_bf16(a0, bfr, acc0[j], 0, 0, 0);
        acc1[j] = __builtin_amdgcn_mfma_f32_16x16x32_bf16(a1, bfr, acc1[j], 0, 0, 0);
      }
    }
#pragma unroll
    for (int j = 0; j < 8; ++j) {
      const int n = n0 + j * 16 + r16;
      const float bo = b_o[n];
#pragma unroll
      for (int r = 0; r < 4; ++r) {
        const long long row0 = t0 + (lane >> 4) * 4 + r;
        float v0 = 1.0f / (1.0f + __expf(-(acc0[j][r] + bo)));
        if (row0 == 0) v0 = caption[n];  // output[0] = caption[0]
        out[row0 * DH + n] = v0;
        const long long row1 = t0 + 16 + (lane >> 4) * 4 + r;
        float v1 = 1.0f / (1.0f + __expf(-(acc1[j][r] + bo)));
        out[row1 * DH + n] = v1;
      }
    }
  }
}

// ---------------------------------------------------------------------------
extern "C" void kernel_launch(void* const* d_in, const int* in_sizes, int n_in,
                              void* d_out, int out_size, void* d_ws,
                              size_t ws_size, hipStream_t stream) {
  const float* features = (const float*)d_in[0];
  const float* caption  = (const float*)d_in[1];
  const float* W_h      = (const float*)d_in[2];
  const float* b_h      = (const float*)d_in[3];
  const float* W_o      = (const float*)d_in[4];
  const float* b_o      = (const float*)d_in[5];
  float* out = (float*)d_out;

  hipLaunchKernelGGL(init_sentinel_kernel, dim3(2048), dim3(256), 0, stream,
                     out);

  const size_t zx_bytes = (size_t)TSEQ * DH * sizeof(float);
  if (ws_size >= zx_bytes) {
    float* zx = (float*)d_ws;
    hipLaunchKernelGGL(zx_mfma_kernel, dim3(TSEQ / R3), dim3(256), 0, stream,
                       zx, caption, W_h, b_h);
    hipLaunchKernelGGL(seq_kernel, dim3(DH / ROWS), dim3(512), 0, stream,
                       features, zx, W_h, out);
  } else {
    hipLaunchKernelGGL(seq_kernel_fb, dim3(DH / ROWS), dim3(512), 0, stream,
                       features, caption, W_h, b_h, out);
  }

  hipLaunchKernelGGL(out_mfma_kernel, dim3(TSEQ / R3), dim3(256), 0, stream,
                     out, W_o, b_o, caption);
}